// Round 1
// 150.090 us; speedup vs baseline: 1.1772x; 1.1772x over previous
//
#include <hip/hip_runtime.h>
#include <stdint.h>

#define Bb 8
#define Dd 256
#define Ll 4096
#define Kk 4096
#define Nn (Bb * Ll)          // 32768 rows
#define OUT0 (Bb * Dd * Ll)   // 8388608

typedef int    int4v   __attribute__((ext_vector_type(4)));
typedef int    int8v   __attribute__((ext_vector_type(8)));
typedef float  floatx4 __attribute__((ext_vector_type(4)));

#define SCALE1 0x7F7F7F7F     // E8M0 exp=127 -> x1.0 for every 32-elem block

union V8 { int8v v; int4v h[2]; };

__device__ __forceinline__ void async_load16(const void* g, void* l) {
    __builtin_amdgcn_global_load_lds((const __attribute__((address_space(1))) void*)g,
                                     (__attribute__((address_space(3))) void*)l, 16, 0, 0);
}

// ---------------------------------------------------------------- kernel 1
// normalize codebook rows, scale x16, cast fp8 e4m3 (block 0 zeroes
// counts + lossacc + done). wn[k][d] = fp8(16 * w[k][d] / max(||w_k||,eps))
__global__ void k_prep(const float* __restrict__ w, unsigned char* __restrict__ wn,
                       int* __restrict__ counts) {
    int blk = blockIdx.x, tid = threadIdx.x;
    if (blk == 0)
        for (int i = tid; i < Kk + 2; i += 256) counts[i] = 0;
    int row  = blk * 4 + (tid >> 6);
    int lane = tid & 63;
    float4 v = ((const float4*)(w + (size_t)row * Dd))[lane];
    float ss = v.x*v.x + v.y*v.y + v.z*v.z + v.w*v.w;
#pragma unroll
    for (int m = 1; m < 64; m <<= 1) ss += __shfl_xor(ss, m, 64);
    float s = 16.0f / fmaxf(sqrtf(ss), 1e-12f);
    int p = __builtin_amdgcn_cvt_pk_fp8_f32(v.x * s, v.y * s, 0, false);
    p     = __builtin_amdgcn_cvt_pk_fp8_f32(v.z * s, v.w * s, p, true);
    ((int*)(wn + (size_t)row * Dd))[lane] = p;
}

// ---------------------------------------------------------------- kernel 2
// fused transpose + fp8 cast + full-col argmax GEMM + gather/loss epilogue.
// 256 blocks x 512 thr: block owns 128 rows x ALL 4096 cols (32 cb-tiles of
// 128 cols through a 2x32KB LDS double buffer). Wave tile 64r x 32c
// (wm=w>>2, wn=w&3). After argmax, block reuses the (dead) 96KB As/Bs LDS
// as a 64x260-stride f32 transpose buffer to gather w[idx] rows, write the
// quantized output, accumulate the MSE loss, histogram counts, and the
// last block computes loss + perplexity (replaces the old k_gather kernel,
// which rocprof showed latency-bound: 58us at 12% HBM, all pipes idle).
// launch_bounds(512,2) -> 256-VGPR cap (af 64 + acc 32 + bf 32 fit, no spill).
__global__ __launch_bounds__(512, 2) void k_gemm_fused(
        const float* __restrict__ x, const unsigned char* __restrict__ Wn,
        const float* __restrict__ w, float* __restrict__ out,
        int* __restrict__ counts) {
    union Smem {
        struct { unsigned char As[128 * 256]; unsigned char Bs[2][128 * 256]; } g;
        float wt[64 * 260];   // 66560 B <= 98304 B, stride 260 (16B-aligned rows)
    };
    __shared__ __align__(16) Smem sm;
    __shared__ unsigned int red[128][4];
    __shared__ int kidx[128];
    __shared__ float wsum[8];
    __shared__ int lastsh;

    float* lossacc = (float*)(counts + Kk);
    int*   done    = counts + Kk + 1;

    int bm = blockIdx.x;
    int tid = threadIdx.x, lane = tid & 63, wv = tid >> 6;
    int wm = wv >> 2, wn = wv & 3;
    int l15 = lane & 15, l4 = lane >> 4;

    // B DMA maps: LDS slot q holds global 16B chunk (col=q>>4, c=(q&15)^(col&15))
    int goff[4], loff[4];
#pragma unroll
    for (int j = 0; j < 4; ++j) {
        int q = j * 512 + tid;            // 0..2047 chunks = 128 cols x 256 B
        int col = q >> 4, p = q & 15;
        goff[j] = col * 256 + ((p ^ (col & 15)) << 4);
        loff[j] = q * 16;
    }

    // prologue DMA: col-tile 0 -> Bs[0] (overlaps transpose below)
#pragma unroll
    for (int j = 0; j < 4; ++j)
        async_load16(Wn + goff[j], (unsigned char*)sm.g.Bs[0] + loff[j]);

    // ---- fused transpose: x slab [256 d][128 l] f32 -> As[l][d] fp8 (swz)
    int b = bm >> 5, l0 = (bm & 31) * 128;
    const float* xs = x + (size_t)b * Dd * Ll + l0;
    int lg = tid & 31, dgr = tid >> 5;    // 32 l-groups x 16 d-groups
#pragma unroll
    for (int i = 0; i < 4; ++i) {
        int d0 = dgr * 4 + i * 64;
        const float* s0 = xs + (size_t)d0 * Ll + lg * 4;
        float4 f0 = *(const float4*)(s0);
        float4 f1 = *(const float4*)(s0 + Ll);
        float4 f2 = *(const float4*)(s0 + 2 * (size_t)Ll);
        float4 f3 = *(const float4*)(s0 + 3 * (size_t)Ll);
#pragma unroll
        for (int jl = 0; jl < 4; ++jl) {
            float a0 = ((const float*)&f0)[jl], a1 = ((const float*)&f1)[jl];
            float a2 = ((const float*)&f2)[jl], a3 = ((const float*)&f3)[jl];
            int pk = __builtin_amdgcn_cvt_pk_fp8_f32(a0, a1, 0, false);
            pk     = __builtin_amdgcn_cvt_pk_fp8_f32(a2, a3, pk, true);
            int l = lg * 4 + jl;
            *(int*)(sm.g.As + l * 256 + (((d0 >> 4) ^ (l & 15)) << 4) + (d0 & 15)) = pk;
        }
    }
    __syncthreads();   // As complete + Bs[0] DMA drained

    // ---- A fragments (64 VGPRs): row = wm*64+fm*16+l15, k = ks*128+l4*32
    int8v af[4][2];
#pragma unroll
    for (int fm = 0; fm < 4; ++fm)
#pragma unroll
        for (int ks = 0; ks < 2; ++ks) {
            int l = wm * 64 + fm * 16 + l15;
            int ch = ks * 8 + l4 * 2;
            V8 u;
            u.h[0] = *(const int4v*)(sm.g.As + l * 256 + ((ch ^ l15) << 4));
            u.h[1] = *(const int4v*)(sm.g.As + l * 256 + (((ch + 1) ^ l15) << 4));
            af[fm][ks] = u.v;
        }

    unsigned int rk[4][4];
#pragma unroll
    for (int fm = 0; fm < 4; ++fm)
#pragma unroll
        for (int r = 0; r < 4; ++r) rk[fm][r] = 0u;

    for (int cb = 0; cb < 32; ++cb) {
        int cur = cb & 1;
        if (cb < 31) {           // prefetch next 128-col tile into other buffer
            const unsigned char* g = Wn + (size_t)(cb + 1) * 128 * 256;
            unsigned char* lb = (unsigned char*)sm.g.Bs[cur ^ 1];
#pragma unroll
            for (int j = 0; j < 4; ++j)
                async_load16(g + goff[j], lb + loff[j]);
        }
        const unsigned char* bb = (const unsigned char*)sm.g.Bs[cur];
        int8v bf[2][2];
#pragma unroll
        for (int fn = 0; fn < 2; ++fn)
#pragma unroll
            for (int ks = 0; ks < 2; ++ks) {
                int col = wn * 32 + fn * 16 + l15;     // 0..127
                int ch = ks * 8 + l4 * 2;
                V8 u;
                u.h[0] = *(const int4v*)(bb + col * 256 + ((ch ^ l15) << 4));
                u.h[1] = *(const int4v*)(bb + col * 256 + (((ch + 1) ^ l15) << 4));
                bf[fn][ks] = u.v;
            }
        floatx4 acc[4][2];
#pragma unroll
        for (int fm = 0; fm < 4; ++fm)
#pragma unroll
            for (int fn = 0; fn < 2; ++fn) {
                floatx4 a = (floatx4)512.0f;    // bias -> positive, int-ordered
                a = __builtin_amdgcn_mfma_scale_f32_16x16x128_f8f6f4(
                        af[fm][0], bf[fn][0], a, 0, 0, 0, SCALE1, 0, SCALE1);
                a = __builtin_amdgcn_mfma_scale_f32_16x16x128_f8f6f4(
                        af[fm][1], bf[fn][1], a, 0, 0, 0, SCALE1, 0, SCALE1);
                acc[fm][fn] = a;
            }
        unsigned int i0 = (unsigned)(cb * 128 + wn * 32 + l15);
#pragma unroll
        for (int fm = 0; fm < 4; ++fm)
#pragma unroll
            for (int r = 0; r < 4; ++r) {
                unsigned int k0 = (__float_as_uint(acc[fm][0][r]) & 0xFFFFF000u) | i0;
                unsigned int k1 = (__float_as_uint(acc[fm][1][r]) & 0xFFFFF000u) | (i0 + 16u);
                unsigned int km = k0 > k1 ? k0 : k1;
                rk[fm][r] = rk[fm][r] > km ? rk[fm][r] : km;
            }
        __syncthreads();         // guards buffer reuse + drains prefetch DMA
    }

    // epilogue: key-max across 16 col-lanes, then across 4 col-strips
#pragma unroll
    for (int fm = 0; fm < 4; ++fm)
#pragma unroll
        for (int r = 0; r < 4; ++r) {
            unsigned int kx = rk[fm][r];
#pragma unroll
            for (int md = 1; md <= 8; md <<= 1) {
                unsigned int o = (unsigned int)__shfl_xor((int)kx, md, 64);
                kx = kx > o ? kx : o;
            }
            if (l15 == 0) red[wm * 64 + fm * 16 + l4 * 4 + r][wn] = kx;
        }
    __syncthreads();
    if (tid < 128) {
        unsigned int k0 = red[tid][0], k1 = red[tid][1];
        unsigned int k2 = red[tid][2], k3 = red[tid][3];
        unsigned int kx = k0 > k1 ? k0 : k1;
        kx = kx > k2 ? kx : k2;
        kx = kx > k3 ? kx : k3;
        int ix = (int)(kx & 0xFFFu);
        kidx[tid] = ix;
        atomicAdd(&counts[ix], 1);
    }
    __syncthreads();   // kidx ready; As/Bs dead -> wt may be written

    // ---- fused gather + out-write + loss: 2 halves of 64 rows each.
    // stage: thread (rr=tid>>3, c8=tid&7) gathers w[kidx[row]] in 128B
    // segments -> wt[rr][*] (stride 260, conflict-free b128 writes).
    // consume: thread (fl=tid&15, dg=tid>>4) covers d=p*32+dg, l=fl*4..+3;
    // x prefetched into regs BEFORE the staging barrier (hides HBM latency
    // under the w-gather). x/out accesses are 256B contiguous per 16 lanes.
    float ls = 0.f;
    int fl = tid & 15, dg = tid >> 4;
    size_t xbase = (size_t)b * Dd * Ll + l0 + fl * 4;
    for (int h = 0; h < 2; ++h) {
        float4 xv[8];
        size_t hb = xbase + h * 64;
#pragma unroll
        for (int p = 0; p < 8; ++p)
            xv[p] = *(const float4*)(x + hb + (size_t)(p * 32 + dg) * Ll);

        int rr = tid >> 3, c8 = tid & 7;
        const float* src = w + (size_t)kidx[h * 64 + rr] * Dd + c8 * 4;
        float4 vv[8];
#pragma unroll
        for (int j = 0; j < 8; ++j) vv[j] = *(const float4*)(src + j * 32);
#pragma unroll
        for (int j = 0; j < 8; ++j)
            *(float4*)&sm.wt[rr * 260 + (c8 + j * 8) * 4] = vv[j];
        __syncthreads();   // wt[h] staged

#pragma unroll
        for (int p = 0; p < 8; ++p) {
            int d = p * 32 + dg;
            float4 qv = { sm.wt[(fl * 4 + 0) * 260 + d], sm.wt[(fl * 4 + 1) * 260 + d],
                          sm.wt[(fl * 4 + 2) * 260 + d], sm.wt[(fl * 4 + 3) * 260 + d] };
            float d0 = qv.x - xv[p].x, d1 = qv.y - xv[p].y;
            float d2 = qv.z - xv[p].z, d3 = qv.w - xv[p].w;
            ls += d0 * d0 + d1 * d1 + d2 * d2 + d3 * d3;
            *(float4*)(out + hb + (size_t)d * Ll) = qv;
        }
        __syncthreads();   // consume done before wt reuse (h=0) / wsum reuse
    }

#pragma unroll
    for (int m = 1; m < 64; m <<= 1) ls += __shfl_xor(ls, m, 64);
    if (lane == 0) wsum[wv] = ls;
    __syncthreads();
    if (tid == 0) {
        atomicAdd(lossacc, wsum[0] + wsum[1] + wsum[2] + wsum[3]
                         + wsum[4] + wsum[5] + wsum[6] + wsum[7]);
        __threadfence();
        lastsh = (atomicAdd(done, 1) == 255);
    }
    __syncthreads();
    if (lastsh) {                 // all blocks' counts/loss atomics now visible
        __threadfence();
        float s = 0.f;
        for (int i = tid; i < Kk; i += 512) {
            float p = (float)counts[i] * (1.0f / Nn);
            s += p * logf(p + 1e-10f);
        }
#pragma unroll
        for (int m = 1; m < 64; m <<= 1) s += __shfl_xor(s, m, 64);
        if (lane == 0) wsum[wv] = s;
        __syncthreads();
        if (tid == 0) {
            out[OUT0]     = lossacc[0] * 1.25f / (float)OUT0;  // q + 0.25*e latent
            out[OUT0 + 1] = expf(-(wsum[0] + wsum[1] + wsum[2] + wsum[3]
                                 + wsum[4] + wsum[5] + wsum[6] + wsum[7]));
        }
    }
}

// ---------------------------------------------------------------- launch
extern "C" void kernel_launch(void* const* d_in, const int* in_sizes, int n_in,
                              void* d_out, int out_size, void* d_ws, size_t ws_size,
                              hipStream_t stream) {
    const float* x = (const float*)d_in[0];   // [B, D, L]
    const float* w = (const float*)d_in[1];   // [K, D]
    float* out = (float*)d_out;
    char* ws = (char*)d_ws;

    unsigned char* wn     = (unsigned char*)ws;            // 1 MB fp8
    int*           counts = (int*)(ws + (1u << 20));       // 16 KB + 8 B

    k_prep      <<<1024, 256, 0, stream>>>(w, wn, counts);
    k_gemm_fused<<<256,  512, 0, stream>>>(x, wn, w, out, counts);
}